// Round 5
// baseline (180.919 us; speedup 1.0000x reference)
//
#include <hip/hip_runtime.h>

typedef unsigned int u32;
typedef unsigned short u16;

#define Cn 128
#define ICn 64
#define Nn 4096
#define Mn 1024

typedef __attribute__((ext_vector_type(8))) short s8v;   // 8 bf16 (4 VGPRs)
typedef __attribute__((ext_vector_type(4))) float f4v;   // 4 fp32 acc

__device__ __forceinline__ float bf2f(u16 u){ union{u32 i; float f;} v; v.i = ((u32)u) << 16; return v.f; }
__device__ __forceinline__ u16 f2bf(float f){ union{float f; u32 i;} v; v.f = f; u32 r = v.i + 0x7fffu + ((v.i >> 16) & 1u); return (u16)(r >> 16); }
__device__ __forceinline__ u32 pk2(float lo, float hi){ return (u32)f2bf(lo) | ((u32)f2bf(hi) << 16); }

// ---------------------------------------------------------------------------
// K1 (MFMA, weight-prep folded in) — R3 version (K-split reverted).
// x^T staged as CHANNEL-PAIRS (ds_write_b32 of 2 bf16), XOR-swizzled cols.
// LDS u16 smem[32768] = 64 KB.
// ---------------------------------------------------------------------------
__global__ __launch_bounds__(256) void k_conv(
    const float* __restrict__ x,
    const float* __restrict__ w1, const float* __restrict__ b1,
    const float* __restrict__ w3, const float* __restrict__ b3,
    const float* __restrict__ w4, const float* __restrict__ b4,
    const float* __restrict__ w5, const float* __restrict__ w2,
    float* __restrict__ t_o, float* __restrict__ p_o, float* __restrict__ g_o)
{
    const int tile = blockIdx.x;   // 0..63
    const int r  = tile >> 1;      // row-pair 0..31
    const int wb = tile & 1;       // half-width 0..1
    const int b  = blockIdx.y;
    const int tid = threadIdx.x;

    __shared__ __align__(16) u16 smem[32768];
    u16* xsT = smem;               // [64][136]
    u16* w1t = smem + 8704;        // [64][136]
    u16* w4t = smem + 17408;       // [64][136]
    float* ph = (float*)&smem[26112]; // [32][68] f32
    u16* w2t = smem + 8704;        // phase B [128][72]
    u16* xgr = smem + 17920;       // phase B [16][72]
    float* u3s = (float*)&smem[30464]; // [129] f32

    // ---- stage x^T as bf16 channel-pairs, swizzled ----
    #pragma unroll
    for (int it = 0; it < 4; ++it) {
        int f = tid + 256 * it;        // 1024 tasks: cp = f>>4, rem = f&15
        int cp = f >> 4, rem = f & 15;
        int rl = rem >> 3, wq = rem & 7;
        const float* src = x + ((size_t)(b * Cn + 2 * cp)) * Nn + (2 * r + rl) * 64 + 32 * wb + 4 * wq;
        float4 v0 = *(const float4*)src;
        float4 v1 = *(const float4*)(src + Nn);
        int lp0 = rl * 32 + 4 * wq;
        int cS = (2 * cp) ^ (wq << 3); // ((lp0+k)>>2)&7 == wq for k=0..3
        *(u32*)&xsT[(lp0 + 0) * 136 + cS] = pk2(v0.x, v1.x);
        *(u32*)&xsT[(lp0 + 1) * 136 + cS] = pk2(v0.y, v1.y);
        *(u32*)&xsT[(lp0 + 2) * 136 + cS] = pk2(v0.z, v1.z);
        *(u32*)&xsT[(lp0 + 3) * 136 + cS] = pk2(v0.w, v1.w);
    }
    // ---- stage W1, W4: f32 load + convert + ds_write_b128 ----
    #pragma unroll
    for (int it = 0; it < 4; ++it) {
        int f = tid + 256 * it;        // 1024 groups of 8: ic = f>>4, cq = f&15
        int ic = f >> 4, cq = f & 15;
        const float4* s1 = (const float4*)&w1[f * 8];
        const float4* s4 = (const float4*)&w4[f * 8];
        float4 a0 = s1[0], a1v = s1[1];
        float4 d0 = s4[0], d1v = s4[1];
        uint4 A, D;
        A.x = pk2(a0.x, a0.y); A.y = pk2(a0.z, a0.w); A.z = pk2(a1v.x, a1v.y); A.w = pk2(a1v.z, a1v.w);
        D.x = pk2(d0.x, d0.y); D.y = pk2(d0.z, d0.w); D.z = pk2(d1v.x, d1v.y); D.w = pk2(d1v.z, d1v.w);
        *(uint4*)&w1t[ic * 136 + 8 * cq] = A;
        *(uint4*)&w4t[ic * 136 + 8 * cq] = D;
    }
    // ---- u3 = w5[:64].W3 (redundant, L2-resident), 2 accumulators ----
    if (tid < 128) {
        float s0 = 0.f, s1 = 0.f;
        #pragma unroll 8
        for (int ic = 0; ic < 64; ic += 2) {
            s0 += w5[ic]     * w3[ic * Cn + tid];
            s1 += w5[ic + 1] * w3[(ic + 1) * Cn + tid];
        }
        u3s[tid] = s0 + s1;
    } else if (tid == 128) {
        float s = 0.f;
        #pragma unroll 16
        for (int ic = 0; ic < 64; ++ic) s += w5[ic] * b3[ic];
        u3s[128] = s;
    }
    __syncthreads();

    const int lane = tid & 63;
    const int wv   = tid >> 6;         // wave 0..3 -> lp block [16wv,16wv+16)
    const int col  = lane & 15;
    const int quad = lane >> 4;

    // ---- dual conv MFMA: D[ic][lp] ----
    f4v acc1[4] = {}, acc4[4] = {};
    const u16* xrow = &xsT[(16 * wv + col) * 136];
    const int xsw = (((16 * wv + col) >> 2) & 7) << 3;
    #pragma unroll
    for (int kb = 0; kb < 4; ++kb) {
        s8v bx = *(const s8v*)&xrow[(kb * 32 + quad * 8) ^ xsw];
        #pragma unroll
        for (int icb = 0; icb < 4; ++icb) {
            s8v a1 = *(const s8v*)&w1t[(icb * 16 + col) * 136 + kb * 32 + quad * 8];
            s8v a4 = *(const s8v*)&w4t[(icb * 16 + col) * 136 + kb * 32 + quad * 8];
            acc1[icb] = __builtin_amdgcn_mfma_f32_16x16x32_bf16(a1, bx, acc1[icb], 0, 0, 0);
            acc4[icb] = __builtin_amdgcn_mfma_f32_16x16x32_bf16(a4, bx, acc4[icb], 0, 0, 0);
        }
    }
    __syncthreads();   // MFMA LDS reads done; w1t/w4t dead

    // ---- a1: horizontal pair max in-register, write half-pool to ph ----
    const int lp = 16 * wv + col;
    const int rl = lp >> 5, wl = lp & 31, pw = wl >> 1;
    const bool wr = (wl & 1) == 0;
    #pragma unroll
    for (int icb = 0; icb < 4; ++icb)
        #pragma unroll
        for (int reg = 0; reg < 4; ++reg) {
            float v = acc1[icb][reg];
            float vm = fmaxf(v, __shfl_xor(v, 1, 64));
            if (wr) ph[(rl * 16 + pw) * 68 + icb * 16 + quad * 4 + reg] = vm;
        }
    __syncthreads();

    // ---- xgr = vertical pool + bias (bf16) ----
    #pragma unroll
    for (int it = 0; it < 4; ++it) {
        int e = tid + 256 * it;        // 1024: pw = e>>6, ic = e&63
        int pwq = e >> 6, ic = e & 63;
        float v = fmaxf(ph[pwq * 68 + ic], ph[(16 + pwq) * 68 + ic]) + b1[ic];
        xgr[pwq * 72 + ic] = f2bf(v);
    }
    // ---- t = u3.x + c3, all 256 threads (4 lanes per pixel) ----
    {
        int px = tid >> 2, part = tid & 3;
        const int tsw = ((px >> 2) & 7) << 3;
        const u16* xr = &xsT[px * 136];
        float s = 0.f;
        #pragma unroll
        for (int cq = 0; cq < 4; ++cq) {
            int u = part * 32 + cq * 8;
            s8v xv = *(const s8v*)&xr[u ^ tsw];
            #pragma unroll
            for (int j = 0; j < 8; ++j) s += u3s[u + j] * bf2f((u16)xv[j]);
        }
        s += __shfl_xor(s, 1, 64);
        s += __shfl_xor(s, 2, 64);
        if (part == 0)
            t_o[(size_t)b * Nn + (2 * r + (px >> 5)) * 64 + 32 * wb + (px & 31)] = s + u3s[128];
    }
    __syncthreads();   // xgr ready; ph consumed

    // ---- stage W2 (f32->bf16) [co][72]; a4 half-pool -> ph ----
    #pragma unroll
    for (int it = 0; it < 4; ++it) {
        int f = tid + 256 * it;        // 1024 groups: co = f>>3, iq = f&7
        int co = f >> 3, iq = f & 7;
        const float4* s2 = (const float4*)&w2[f * 8];
        float4 a0 = s2[0], a1v = s2[1];
        uint4 V;
        V.x = pk2(a0.x, a0.y); V.y = pk2(a0.z, a0.w); V.z = pk2(a1v.x, a1v.y); V.w = pk2(a1v.z, a1v.w);
        *(uint4*)&w2t[co * 72 + 8 * iq] = V;
    }
    #pragma unroll
    for (int icb = 0; icb < 4; ++icb)
        #pragma unroll
        for (int reg = 0; reg < 4; ++reg) {
            float v = acc4[icb][reg];
            float vm = fmaxf(v, __shfl_xor(v, 1, 64));
            if (wr) ph[(rl * 16 + pw) * 68 + icb * 16 + quad * 4 + reg] = vm;
        }
    __syncthreads();

    // ---- g = xgr . W2^T via MFMA: wave wv -> co blocks {2wv, 2wv+1} ----
    #pragma unroll
    for (int cob2 = 0; cob2 < 2; ++cob2) {
        int cob = 2 * wv + cob2;
        f4v gacc = {};
        #pragma unroll
        for (int kb = 0; kb < 2; ++kb) {
            s8v a  = *(const s8v*)&xgr[col * 72 + kb * 32 + quad * 8];
            s8v bb = *(const s8v*)&w2t[(cob * 16 + col) * 72 + kb * 32 + quad * 8];
            gacc = __builtin_amdgcn_mfma_f32_16x16x32_bf16(a, bb, gacc, 0, 0, 0);
        }
        #pragma unroll
        for (int reg = 0; reg < 4; ++reg) {
            int pwr = quad * 4 + reg;
            int m = r * 32 + wb * 16 + pwr;
            g_o[((size_t)b * Mn + m) * 128 + cob * 16 + col] = gacc[reg];
        }
    }

    // ---- p from a4 pool ----
    if (tid < 16) {
        float s = 0.f;
        #pragma unroll 8
        for (int ic = 0; ic < 64; ++ic) {
            float pv = fmaxf(ph[tid * 68 + ic], ph[(16 + tid) * 68 + ic]) + b4[ic];
            s += w5[64 + ic] * pv;
        }
        p_o[(size_t)b * Mn + r * 32 + wb * 16 + tid] = s;
    }
}

// ---------------------------------------------------------------------------
// K2 (fused rank + suffix-scan): grid (4 co-splits, 8 b), 512 threads.
// Each block REDUNDANTLY ranks all 1024 keys in LDS (2 keys/thread, float4
// broadcast reads), then does the full suffix scan for its 32 co columns:
// per-thread 64-row partials -> LDS suffix offsets -> 64-row walk writing
// SAB[b][j][co] = {suffix g, suffix p*g}. csp==0 also writes sorted ps.
// Replaces k_rank + k_scanA + k_scanC (2 launches + csab/perm removed).
// ---------------------------------------------------------------------------
__global__ __launch_bounds__(512) void k_scan(
    const float* __restrict__ p, const float* __restrict__ g,
    float* __restrict__ ps, float2* __restrict__ SAB)
{
    const int csp = blockIdx.x;    // 0..3 -> co base 32*csp
    const int b   = blockIdx.y;
    const int tid = threadIdx.x;

    __shared__ __align__(16) float pls[1024];
    __shared__ __align__(16) float skey[1024];
    __shared__ int   sm[1024];
    __shared__ float pA[16][32], pB[16][32];

    pls[tid]       = p[b * 1024 + tid];
    pls[tid + 512] = p[b * 1024 + tid + 512];
    __syncthreads();

    // ---- rank 2 keys per thread (ascending, stable) ----
    {
        const int m0 = tid, m1 = tid + 512;
        const float k0 = pls[m0], k1 = pls[m1];
        int r0 = 0, r1 = 0;
        #pragma unroll 4
        for (int j4 = 0; j4 < 256; ++j4) {
            float4 v = *(const float4*)&pls[4 * j4];
            int j = 4 * j4;
            r0 += (v.x < k0 || (v.x == k0 && (j + 0) < m0)) ? 1 : 0;
            r0 += (v.y < k0 || (v.y == k0 && (j + 1) < m0)) ? 1 : 0;
            r0 += (v.z < k0 || (v.z == k0 && (j + 2) < m0)) ? 1 : 0;
            r0 += (v.w < k0 || (v.w == k0 && (j + 3) < m0)) ? 1 : 0;
            r1 += (v.x < k1 || (v.x == k1 && (j + 0) < m1)) ? 1 : 0;
            r1 += (v.y < k1 || (v.y == k1 && (j + 1) < m1)) ? 1 : 0;
            r1 += (v.z < k1 || (v.z == k1 && (j + 2) < m1)) ? 1 : 0;
            r1 += (v.w < k1 || (v.w == k1 && (j + 3) < m1)) ? 1 : 0;
        }
        skey[r0] = k0; sm[r0] = m0;
        skey[r1] = k1; sm[r1] = m1;
        if (csp == 0) {
            ps[b * 1024 + r0] = k0;
            ps[b * 1024 + r1] = k1;
        }
    }
    __syncthreads();

    const int co32 = tid & 31;
    const int grp  = tid >> 5;               // 0..15, rows [64grp, 64grp+64)
    const int co   = csp * 32 + co32;
    const float* gb = g + (size_t)b * Mn * 128 + co;

    // ---- per-thread partials over 64 rows ----
    float sA = 0.f, sB = 0.f;
    #pragma unroll 8
    for (int j = 64 * grp; j < 64 * grp + 64; ++j) {
        float gv = gb[sm[j] * 128];
        sA += gv; sB += skey[j] * gv;
    }
    pA[grp][co32] = sA; pB[grp][co32] = sB;
    __syncthreads();

    float rA = 0.f, rB = 0.f;
    #pragma unroll
    for (int g2 = grp + 1; g2 < 16; ++g2) { rA += pA[g2][co32]; rB += pB[g2][co32]; }

    float2* SABb = SAB + (size_t)b * 1025 * 128 + co;
    if (grp == 0) SABb[1024 * 128] = make_float2(0.f, 0.f);

    // ---- walk descending, writing suffix sums (re-gather, L2-warm) ----
    #pragma unroll 8
    for (int j = 64 * grp + 63; j >= 64 * grp; --j) {
        float gv = gb[sm[j] * 128];
        rA += gv;
        rB += skey[j] * gv;
        SABb[j * 128] = make_float2(rA, rB);
    }
}

// ---------------------------------------------------------------------------
// K6: out = ((t[n]*SA[k(n)][co] + SB[k(n)][co])/M)*sc[co] + bs[co] + x
// 512 threads; SA/SB prefetched per-sub into registers (overlap with compute).
// ---------------------------------------------------------------------------
__global__ __launch_bounds__(512) void k_final(
    const float* __restrict__ x, const float* __restrict__ t,
    const float* __restrict__ ps, const float2* __restrict__ SAB,
    const float* __restrict__ b2, const float* __restrict__ gamma, const float* __restrict__ beta,
    const float* __restrict__ mean, const float* __restrict__ var,
    float* __restrict__ out)
{
    const int nt = blockIdx.x;
    const int b = blockIdx.y;
    const int tid = threadIdx.x;
    const int n0 = nt * 128;
    __shared__ float psl[1024];
    __shared__ float tl[128];
    __shared__ int   kl[128];
    __shared__ float sc[128], bs[128];
    __shared__ float sa_s[32][129], sb_s[32][129];

    #pragma unroll
    for (int it = 0; it < 2; ++it) psl[tid + 512 * it] = ps[b * 1024 + tid + 512 * it];
    __syncthreads();
    if (tid < 128) {
        float tv = t[(size_t)b * Nn + n0 + tid];
        tl[tid] = tv;
        float key = -tv;
        int lo = 0, hi = 1024;
        while (lo < hi) { int mid = (lo + hi) >> 1; if (psl[mid] > key) hi = mid; else lo = mid + 1; }
        kl[tid] = lo;
    } else if (tid < 256) {
        int co = tid - 128;
        float s = gamma[co] * rsqrtf(var[co] + 1e-5f);
        sc[co] = s * (1.0f / 1024.0f);             // fold 1/M into BN scale
        bs[co] = (b2[co] - mean[co]) * s + beta[co];
    }
    __syncthreads();

    // prefetch pipeline: 8 float2 rows per thread per sub
    float2 pf[8], pf2[8];
    {
        #pragma unroll
        for (int i2 = 0; i2 < 8; ++i2) {
            int f = tid + 512 * i2;
            int rowl = f >> 7, co = f & 127;
            pf[i2] = SAB[((size_t)b * 1025 + kl[rowl]) * 128 + co];
        }
    }
    for (int sub = 0; sub < 4; ++sub) {
        #pragma unroll
        for (int i2 = 0; i2 < 8; ++i2) {
            int f = tid + 512 * i2;
            int rowl = f >> 7, co = f & 127;
            sa_s[rowl][co] = pf[i2].x;
            sb_s[rowl][co] = pf[i2].y;
        }
        if (sub < 3) {
            #pragma unroll
            for (int i2 = 0; i2 < 8; ++i2) {
                int f = tid + 512 * i2;
                int rowl = f >> 7, co = f & 127;
                pf2[i2] = SAB[((size_t)b * 1025 + kl[(sub + 1) * 32 + rowl]) * 128 + co];
            }
        }
        __syncthreads();
        #pragma unroll
        for (int it = 0; it < 2; ++it) {
            int f = tid + 512 * it;
            int co = f >> 3, nn0 = (f & 7) * 4;
            size_t gidx = ((size_t)b * Cn + co) * Nn + n0 + sub * 32 + nn0;
            float4 xv = *(const float4*)&x[gidx];
            float scv = sc[co], bsv = bs[co];
            float4 o;
            float v0 = tl[sub*32+nn0+0] * sa_s[nn0+0][co] + sb_s[nn0+0][co];
            float v1 = tl[sub*32+nn0+1] * sa_s[nn0+1][co] + sb_s[nn0+1][co];
            float v2 = tl[sub*32+nn0+2] * sa_s[nn0+2][co] + sb_s[nn0+2][co];
            float v3 = tl[sub*32+nn0+3] * sa_s[nn0+3][co] + sb_s[nn0+3][co];
            o.x = v0 * scv + bsv + xv.x;
            o.y = v1 * scv + bsv + xv.y;
            o.z = v2 * scv + bsv + xv.z;
            o.w = v3 * scv + bsv + xv.w;
            *(float4*)&out[gidx] = o;
        }
        __syncthreads();
        #pragma unroll
        for (int i2 = 0; i2 < 8; ++i2) pf[i2] = pf2[i2];
    }
}

// ---------------------------------------------------------------------------
extern "C" void kernel_launch(void* const* d_in, const int* in_sizes, int n_in,
                              void* d_out, int out_size, void* d_ws, size_t ws_size,
                              hipStream_t stream)
{
    const float* x  = (const float*)d_in[0];
    const float* w1 = (const float*)d_in[1];
    const float* b1 = (const float*)d_in[2];
    const float* w3 = (const float*)d_in[3];
    const float* b3 = (const float*)d_in[4];
    const float* w4 = (const float*)d_in[5];
    const float* b4 = (const float*)d_in[6];
    const float* w5 = (const float*)d_in[7];
    const float* w2 = (const float*)d_in[8];
    const float* b2 = (const float*)d_in[9];
    const float* gm = (const float*)d_in[10];
    const float* bt = (const float*)d_in[11];
    const float* mn = (const float*)d_in[12];
    const float* vr = (const float*)d_in[13];
    float* out = (float*)d_out;

    float* ws = (float*)d_ws;
    const size_t FTOT = 3823872;           // floats (~15.3 MB)
    if (ws_size < FTOT * sizeof(float)) return;

    float*  t_w  = ws;                      // 32768
    float*  p_w  = ws + 32768;              // 8192
    float*  ps_w = ws + 40960;              // 8192
    float*  g_w  = ws + 581632;             // 1048576
    float2* SAB  = (float2*)(ws + 1695744); // 1025*128*8 fl2 = 2099200 fl

    k_conv <<<dim3(64, 8), 256, 0, stream>>>(x, w1, b1, w3, b3, w4, b4, w5, w2,
                                             t_w, p_w, g_w);
    k_scan <<<dim3(4, 8),  512, 0, stream>>>(p_w, g_w, ps_w, SAB);
    k_final<<<dim3(32, 8), 512, 0, stream>>>(x, t_w, ps_w, SAB, b2, gm, bt, mn, vr, out);
}

// Round 6
// 121.070 us; speedup vs baseline: 1.4943x; 1.4943x over previous
//
#include <hip/hip_runtime.h>

typedef unsigned int u32;
typedef unsigned short u16;

#define Cn 128
#define ICn 64
#define Nn 4096
#define Mn 1024

typedef __attribute__((ext_vector_type(8))) short s8v;   // 8 bf16 (4 VGPRs)
typedef __attribute__((ext_vector_type(4))) float f4v;   // 4 fp32 acc

__device__ __forceinline__ float bf2f(u16 u){ union{u32 i; float f;} v; v.i = ((u32)u) << 16; return v.f; }
// HW packed f32->bf16 (RNE), replaces ~10-op bit-trick per pair.
__device__ __forceinline__ u32 pk2(float lo, float hi){
    u32 r;
    asm("v_cvt_pk_bf16_f32 %0, %1, %2" : "=v"(r) : "v"(lo), "v"(hi));
    return r;
}
__device__ __forceinline__ u16 f2bf(float f){
    u32 r;
    asm("v_cvt_pk_bf16_f32 %0, %1, %2" : "=v"(r) : "v"(f), "v"(f));
    return (u16)r;
}

// ---------------------------------------------------------------------------
// K1 (MFMA, weight-prep folded in) — R3 structure + cvt_pk staging.
// x^T staged as CHANNEL-PAIRS (ds_write_b32 of 2 bf16), XOR-swizzled cols.
// LDS u16 smem[32768] = 64 KB.
// ---------------------------------------------------------------------------
__global__ __launch_bounds__(256) void k_conv(
    const float* __restrict__ x,
    const float* __restrict__ w1, const float* __restrict__ b1,
    const float* __restrict__ w3, const float* __restrict__ b3,
    const float* __restrict__ w4, const float* __restrict__ b4,
    const float* __restrict__ w5, const float* __restrict__ w2,
    float* __restrict__ t_o, float* __restrict__ p_o, float* __restrict__ g_o)
{
    const int tile = blockIdx.x;   // 0..63
    const int r  = tile >> 1;      // row-pair 0..31
    const int wb = tile & 1;       // half-width 0..1
    const int b  = blockIdx.y;
    const int tid = threadIdx.x;

    __shared__ __align__(16) u16 smem[32768];
    u16* xsT = smem;               // [64][136]
    u16* w1t = smem + 8704;        // [64][136]
    u16* w4t = smem + 17408;       // [64][136]
    float* ph = (float*)&smem[26112]; // [32][68] f32
    u16* w2t = smem + 8704;        // phase B [128][72]
    u16* xgr = smem + 17920;       // phase B [16][72]
    float* u3s = (float*)&smem[30464]; // [129] f32

    // ---- stage x^T as bf16 channel-pairs, swizzled ----
    #pragma unroll
    for (int it = 0; it < 4; ++it) {
        int f = tid + 256 * it;        // 1024 tasks: cp = f>>4, rem = f&15
        int cp = f >> 4, rem = f & 15;
        int rl = rem >> 3, wq = rem & 7;
        const float* src = x + ((size_t)(b * Cn + 2 * cp)) * Nn + (2 * r + rl) * 64 + 32 * wb + 4 * wq;
        float4 v0 = *(const float4*)src;
        float4 v1 = *(const float4*)(src + Nn);
        int lp0 = rl * 32 + 4 * wq;
        int cS = (2 * cp) ^ (wq << 3); // ((lp0+k)>>2)&7 == wq for k=0..3
        *(u32*)&xsT[(lp0 + 0) * 136 + cS] = pk2(v0.x, v1.x);
        *(u32*)&xsT[(lp0 + 1) * 136 + cS] = pk2(v0.y, v1.y);
        *(u32*)&xsT[(lp0 + 2) * 136 + cS] = pk2(v0.z, v1.z);
        *(u32*)&xsT[(lp0 + 3) * 136 + cS] = pk2(v0.w, v1.w);
    }
    // ---- stage W1, W4: f32 load + cvt_pk + ds_write_b128 ----
    #pragma unroll
    for (int it = 0; it < 4; ++it) {
        int f = tid + 256 * it;        // 1024 groups of 8: ic = f>>4, cq = f&15
        int ic = f >> 4, cq = f & 15;
        const float4* s1 = (const float4*)&w1[f * 8];
        const float4* s4 = (const float4*)&w4[f * 8];
        float4 a0 = s1[0], a1v = s1[1];
        float4 d0 = s4[0], d1v = s4[1];
        uint4 A, D;
        A.x = pk2(a0.x, a0.y); A.y = pk2(a0.z, a0.w); A.z = pk2(a1v.x, a1v.y); A.w = pk2(a1v.z, a1v.w);
        D.x = pk2(d0.x, d0.y); D.y = pk2(d0.z, d0.w); D.z = pk2(d1v.x, d1v.y); D.w = pk2(d1v.z, d1v.w);
        *(uint4*)&w1t[ic * 136 + 8 * cq] = A;
        *(uint4*)&w4t[ic * 136 + 8 * cq] = D;
    }
    // ---- u3 = w5[:64].W3 (redundant, L2-resident), 2 accumulators ----
    if (tid < 128) {
        float s0 = 0.f, s1 = 0.f;
        #pragma unroll 8
        for (int ic = 0; ic < 64; ic += 2) {
            s0 += w5[ic]     * w3[ic * Cn + tid];
            s1 += w5[ic + 1] * w3[(ic + 1) * Cn + tid];
        }
        u3s[tid] = s0 + s1;
    } else if (tid == 128) {
        float s = 0.f;
        #pragma unroll 16
        for (int ic = 0; ic < 64; ++ic) s += w5[ic] * b3[ic];
        u3s[128] = s;
    }
    __syncthreads();

    const int lane = tid & 63;
    const int wv   = tid >> 6;         // wave 0..3 -> lp block [16wv,16wv+16)
    const int col  = lane & 15;
    const int quad = lane >> 4;

    // ---- dual conv MFMA: D[ic][lp] ----
    f4v acc1[4] = {}, acc4[4] = {};
    const u16* xrow = &xsT[(16 * wv + col) * 136];
    const int xsw = (((16 * wv + col) >> 2) & 7) << 3;
    #pragma unroll
    for (int kb = 0; kb < 4; ++kb) {
        s8v bx = *(const s8v*)&xrow[(kb * 32 + quad * 8) ^ xsw];
        #pragma unroll
        for (int icb = 0; icb < 4; ++icb) {
            s8v a1 = *(const s8v*)&w1t[(icb * 16 + col) * 136 + kb * 32 + quad * 8];
            s8v a4 = *(const s8v*)&w4t[(icb * 16 + col) * 136 + kb * 32 + quad * 8];
            acc1[icb] = __builtin_amdgcn_mfma_f32_16x16x32_bf16(a1, bx, acc1[icb], 0, 0, 0);
            acc4[icb] = __builtin_amdgcn_mfma_f32_16x16x32_bf16(a4, bx, acc4[icb], 0, 0, 0);
        }
    }
    __syncthreads();   // MFMA LDS reads done; w1t/w4t dead

    // ---- a1: horizontal pair max in-register, write half-pool to ph ----
    const int lp = 16 * wv + col;
    const int rl = lp >> 5, wl = lp & 31, pw = wl >> 1;
    const bool wr = (wl & 1) == 0;
    #pragma unroll
    for (int icb = 0; icb < 4; ++icb)
        #pragma unroll
        for (int reg = 0; reg < 4; ++reg) {
            float v = acc1[icb][reg];
            float vm = fmaxf(v, __shfl_xor(v, 1, 64));
            if (wr) ph[(rl * 16 + pw) * 68 + icb * 16 + quad * 4 + reg] = vm;
        }
    __syncthreads();

    // ---- xgr = vertical pool + bias (bf16) ----
    #pragma unroll
    for (int it = 0; it < 4; ++it) {
        int e = tid + 256 * it;        // 1024: pw = e>>6, ic = e&63
        int pwq = e >> 6, ic = e & 63;
        float v = fmaxf(ph[pwq * 68 + ic], ph[(16 + pwq) * 68 + ic]) + b1[ic];
        xgr[pwq * 72 + ic] = f2bf(v);
    }
    // ---- t = u3.x + c3, all 256 threads (4 lanes per pixel) ----
    {
        int px = tid >> 2, part = tid & 3;
        const int tsw = ((px >> 2) & 7) << 3;
        const u16* xr = &xsT[px * 136];
        float s = 0.f;
        #pragma unroll
        for (int cq = 0; cq < 4; ++cq) {
            int u = part * 32 + cq * 8;
            s8v xv = *(const s8v*)&xr[u ^ tsw];
            #pragma unroll
            for (int j = 0; j < 8; ++j) s += u3s[u + j] * bf2f((u16)xv[j]);
        }
        s += __shfl_xor(s, 1, 64);
        s += __shfl_xor(s, 2, 64);
        if (part == 0)
            t_o[(size_t)b * Nn + (2 * r + (px >> 5)) * 64 + 32 * wb + (px & 31)] = s + u3s[128];
    }
    __syncthreads();   // xgr ready; ph consumed

    // ---- stage W2 (cvt_pk) [co][72]; a4 half-pool -> ph ----
    #pragma unroll
    for (int it = 0; it < 4; ++it) {
        int f = tid + 256 * it;        // 1024 groups: co = f>>3, iq = f&7
        int co = f >> 3, iq = f & 7;
        const float4* s2 = (const float4*)&w2[f * 8];
        float4 a0 = s2[0], a1v = s2[1];
        uint4 V;
        V.x = pk2(a0.x, a0.y); V.y = pk2(a0.z, a0.w); V.z = pk2(a1v.x, a1v.y); V.w = pk2(a1v.z, a1v.w);
        *(uint4*)&w2t[co * 72 + 8 * iq] = V;
    }
    #pragma unroll
    for (int icb = 0; icb < 4; ++icb)
        #pragma unroll
        for (int reg = 0; reg < 4; ++reg) {
            float v = acc4[icb][reg];
            float vm = fmaxf(v, __shfl_xor(v, 1, 64));
            if (wr) ph[(rl * 16 + pw) * 68 + icb * 16 + quad * 4 + reg] = vm;
        }
    __syncthreads();

    // ---- g = xgr . W2^T via MFMA: wave wv -> co blocks {2wv, 2wv+1} ----
    #pragma unroll
    for (int cob2 = 0; cob2 < 2; ++cob2) {
        int cob = 2 * wv + cob2;
        f4v gacc = {};
        #pragma unroll
        for (int kb = 0; kb < 2; ++kb) {
            s8v a  = *(const s8v*)&xgr[col * 72 + kb * 32 + quad * 8];
            s8v bb = *(const s8v*)&w2t[(cob * 16 + col) * 72 + kb * 32 + quad * 8];
            gacc = __builtin_amdgcn_mfma_f32_16x16x32_bf16(a, bb, gacc, 0, 0, 0);
        }
        #pragma unroll
        for (int reg = 0; reg < 4; ++reg) {
            int pwr = quad * 4 + reg;
            int m = r * 32 + wb * 16 + pwr;
            g_o[((size_t)b * Mn + m) * 128 + cob * 16 + col] = gacc[reg];
        }
    }

    // ---- p from a4 pool ----
    if (tid < 16) {
        float s = 0.f;
        #pragma unroll 8
        for (int ic = 0; ic < 64; ++ic) {
            float pv = fmaxf(ph[tid * 68 + ic], ph[(16 + tid) * 68 + ic]) + b4[ic];
            s += w5[64 + ic] * pv;
        }
        p_o[(size_t)b * Mn + r * 32 + wb * 16 + tid] = s;
    }
}

// ---------------------------------------------------------------------------
// K3: rank-by-counting, 512 threads: 16 lanes per key, 32 keys per block.
// ---------------------------------------------------------------------------
__global__ __launch_bounds__(512) void k_rank(
    const float* __restrict__ p, float* __restrict__ ps, int* __restrict__ perm)
{
    const int seg = blockIdx.x;    // 0..31
    const int b   = blockIdx.y;
    const int tid = threadIdx.x;
    __shared__ float pls[1024];
    #pragma unroll
    for (int it = 0; it < 2; ++it) pls[tid + 512 * it] = p[b * 1024 + tid + 512 * it];
    __syncthreads();
    const int m = seg * 32 + (tid >> 4);
    const int sub = tid & 15;
    const float key = pls[m];
    int rank = 0;
    #pragma unroll 8
    for (int jj = 0; jj < 64; ++jj) {
        int j = sub + jj * 16;
        float v = pls[j];
        rank += (v < key || (v == key && j < m)) ? 1 : 0;
    }
    rank += __shfl_xor(rank, 1, 64);
    rank += __shfl_xor(rank, 2, 64);
    rank += __shfl_xor(rank, 4, 64);
    rank += __shfl_xor(rank, 8, 64);
    if (sub == 0) {
        ps[b * 1024 + rank]   = key;
        perm[b * 1024 + rank] = m;
    }
}

// ---------------------------------------------------------------------------
// K4: per 32-j segment chunk sums -> csab[seg][co] = {sum g, sum p*g} (float2)
// ---------------------------------------------------------------------------
__global__ __launch_bounds__(512) void k_scanA(
    const float* __restrict__ g, const float* __restrict__ ps, const int* __restrict__ perm,
    float2* __restrict__ csab)
{
    const int seg = blockIdx.x;
    const int b = blockIdx.y;
    const int tid = threadIdx.x;
    const int co = tid & 127, jh = tid >> 7;   // jh 0..3
    __shared__ float redA[4][128], redB[4][128];
    __shared__ float pl[32];
    __shared__ int   pml[32];
    if (tid < 32) { pl[tid] = ps[b * 1024 + seg * 32 + tid]; pml[tid] = perm[b * 1024 + seg * 32 + tid]; }
    __syncthreads();
    float sA = 0.f, sB = 0.f;
    #pragma unroll
    for (int jj = jh * 8; jj < jh * 8 + 8; ++jj) {
        float gv = g[((size_t)b * Mn + pml[jj]) * 128 + co];
        sA += gv; sB += pl[jj] * gv;
    }
    redA[jh][co] = sA; redB[jh][co] = sB;
    __syncthreads();
    if (tid < 128) {
        float2 v;
        v.x = (redA[0][tid] + redA[1][tid]) + (redA[2][tid] + redA[3][tid]);
        v.y = (redB[0][tid] + redB[1][tid]) + (redB[2][tid] + redB[3][tid]);
        csab[(b * 32 + seg) * 128 + tid] = v;
    }
}

// ---------------------------------------------------------------------------
// K5: suffix-sum walk -> SAB[b][k][co] (float2), k in [0,1024].
// 512 threads: all stage gs; threads 0..127 (=co) walk + float2 write.
// ---------------------------------------------------------------------------
__global__ __launch_bounds__(512) void k_scanC(
    const float* __restrict__ g, const float* __restrict__ ps, const int* __restrict__ perm,
    const float2* __restrict__ csab, float2* __restrict__ SAB)
{
    const int seg = blockIdx.x;
    const int b = blockIdx.y;
    const int tid = threadIdx.x;
    __shared__ float gs[32 * 128];
    __shared__ float pl[32];
    __shared__ int   pml[32];
    if (tid < 32) { pl[tid] = ps[b * 1024 + seg * 32 + tid]; pml[tid] = perm[b * 1024 + seg * 32 + tid]; }
    __syncthreads();
    #pragma unroll
    for (int it = 0; it < 8; ++it) {
        int f = tid + 512 * it;
        int jj = f >> 7, co = f & 127;
        gs[jj * 128 + co] = g[((size_t)b * Mn + pml[jj]) * 128 + co];
    }
    __syncthreads();

    if (tid < 128) {
        const int co = tid;
        float rA = 0.f, rB = 0.f;
        #pragma unroll 4
        for (int s2 = seg + 1; s2 < 32; ++s2) {
            float2 v = csab[(b * 32 + s2) * 128 + co];
            rA += v.x; rB += v.y;
        }
        if (seg == 31) SAB[((size_t)b * 1025 + 1024) * 128 + co] = make_float2(0.f, 0.f);
        #pragma unroll
        for (int jj = 31; jj >= 0; --jj) {
            float gv = gs[jj * 128 + co];
            rA += gv;
            rB += pl[jj] * gv;
            SAB[((size_t)b * 1025 + seg * 32 + jj) * 128 + co] = make_float2(rA, rB);
        }
    }
}

// ---------------------------------------------------------------------------
// K6: out = ((t[n]*SA[k(n)][co] + SB[k(n)][co])/M)*sc[co] + bs[co] + x
// Grid (64,8) x 256 thr: 512 blocks (2/CU) -> cross-block latency hiding;
// 64 n per block, 2 subs of 32 rows, same LDS-coalesced SAB staging.
// ---------------------------------------------------------------------------
__global__ __launch_bounds__(256) void k_final(
    const float* __restrict__ x, const float* __restrict__ t,
    const float* __restrict__ ps, const float2* __restrict__ SAB,
    const float* __restrict__ b2, const float* __restrict__ gamma, const float* __restrict__ beta,
    const float* __restrict__ mean, const float* __restrict__ var,
    float* __restrict__ out)
{
    const int nt = blockIdx.x;     // 0..63
    const int b = blockIdx.y;
    const int tid = threadIdx.x;
    const int n0 = nt * 64;
    __shared__ float psl[1024];
    __shared__ float tl[64];
    __shared__ int   kl[64];
    __shared__ float sc[128], bs[128];
    __shared__ float sa_s[32][129], sb_s[32][129];

    #pragma unroll
    for (int it = 0; it < 4; ++it) psl[tid + 256 * it] = ps[b * 1024 + tid + 256 * it];
    __syncthreads();
    if (tid < 64) {
        float tv = t[(size_t)b * Nn + n0 + tid];
        tl[tid] = tv;
        float key = -tv;
        int lo = 0, hi = 1024;
        while (lo < hi) { int mid = (lo + hi) >> 1; if (psl[mid] > key) hi = mid; else lo = mid + 1; }
        kl[tid] = lo;
    } else if (tid >= 128) {
        int co = tid - 128;
        float s = gamma[co] * rsqrtf(var[co] + 1e-5f);
        sc[co] = s * (1.0f / 1024.0f);             // fold 1/M into BN scale
        bs[co] = (b2[co] - mean[co]) * s + beta[co];
    }
    __syncthreads();

    // prefetch pipeline: 16 float2 rows per thread per sub (4096 tasks / 256)
    float2 pf[16], pf2[16];
    #pragma unroll
    for (int i2 = 0; i2 < 16; ++i2) {
        int f = tid + 256 * i2;
        int rowl = f >> 7, co = f & 127;
        pf[i2] = SAB[((size_t)b * 1025 + kl[rowl]) * 128 + co];
    }
    #pragma unroll
    for (int sub = 0; sub < 2; ++sub) {
        #pragma unroll
        for (int i2 = 0; i2 < 16; ++i2) {
            int f = tid + 256 * i2;
            int rowl = f >> 7, co = f & 127;
            sa_s[rowl][co] = pf[i2].x;
            sb_s[rowl][co] = pf[i2].y;
        }
        if (sub < 1) {
            #pragma unroll
            for (int i2 = 0; i2 < 16; ++i2) {
                int f = tid + 256 * i2;
                int rowl = f >> 7, co = f & 127;
                pf2[i2] = SAB[((size_t)b * 1025 + kl[32 + rowl]) * 128 + co];
            }
        }
        __syncthreads();
        #pragma unroll
        for (int it = 0; it < 4; ++it) {
            int f = tid + 256 * it;
            int co = f >> 3, nn0 = (f & 7) * 4;
            size_t gidx = ((size_t)b * Cn + co) * Nn + n0 + sub * 32 + nn0;
            float4 xv = *(const float4*)&x[gidx];
            float scv = sc[co], bsv = bs[co];
            float4 o;
            float v0 = tl[sub*32+nn0+0] * sa_s[nn0+0][co] + sb_s[nn0+0][co];
            float v1 = tl[sub*32+nn0+1] * sa_s[nn0+1][co] + sb_s[nn0+1][co];
            float v2 = tl[sub*32+nn0+2] * sa_s[nn0+2][co] + sb_s[nn0+2][co];
            float v3 = tl[sub*32+nn0+3] * sa_s[nn0+3][co] + sb_s[nn0+3][co];
            o.x = v0 * scv + bsv + xv.x;
            o.y = v1 * scv + bsv + xv.y;
            o.z = v2 * scv + bsv + xv.z;
            o.w = v3 * scv + bsv + xv.w;
            *(float4*)&out[gidx] = o;
        }
        __syncthreads();
        #pragma unroll
        for (int i2 = 0; i2 < 16; ++i2) pf[i2] = pf2[i2];
    }
}

// ---------------------------------------------------------------------------
extern "C" void kernel_launch(void* const* d_in, const int* in_sizes, int n_in,
                              void* d_out, int out_size, void* d_ws, size_t ws_size,
                              hipStream_t stream)
{
    const float* x  = (const float*)d_in[0];
    const float* w1 = (const float*)d_in[1];
    const float* b1 = (const float*)d_in[2];
    const float* w3 = (const float*)d_in[3];
    const float* b3 = (const float*)d_in[4];
    const float* w4 = (const float*)d_in[5];
    const float* b4 = (const float*)d_in[6];
    const float* w5 = (const float*)d_in[7];
    const float* w2 = (const float*)d_in[8];
    const float* b2 = (const float*)d_in[9];
    const float* gm = (const float*)d_in[10];
    const float* bt = (const float*)d_in[11];
    const float* mn = (const float*)d_in[12];
    const float* vr = (const float*)d_in[13];
    float* out = (float*)d_out;

    float* ws = (float*)d_ws;
    const size_t FTOT = 3823872;           // floats (~15.3 MB)
    if (ws_size < FTOT * sizeof(float)) return;

    float*  t_w  = ws;                      // 32768
    float*  p_w  = ws + 32768;              // 8192
    float*  ps_w = ws + 40960;              // 8192
    int*    pm_w = (int*)(ws + 49152);      // 8192
    float*  g_w  = ws + 581632;             // 1048576
    float2* csab = (float2*)(ws + 1630208); // 8192 float2 = 65536 fl
    float2* SAB  = (float2*)(ws + 1695744); // 1025*128*8 fl2 = 2099200 fl

    k_conv <<<dim3(64, 8), 256, 0, stream>>>(x, w1, b1, w3, b3, w4, b4, w5, w2,
                                             t_w, p_w, g_w);
    k_rank <<<dim3(32, 8), 512, 0, stream>>>(p_w, ps_w, pm_w);
    k_scanA<<<dim3(32, 8), 512, 0, stream>>>(g_w, ps_w, pm_w, csab);
    k_scanC<<<dim3(32, 8), 512, 0, stream>>>(g_w, ps_w, pm_w, csab, SAB);
    k_final<<<dim3(64, 8), 256, 0, stream>>>(x, t_w, ps_w, SAB, b2, gm, bt, mn, vr, out);
}

// Round 7
// 118.037 us; speedup vs baseline: 1.5327x; 1.0257x over previous
//
#include <hip/hip_runtime.h>

typedef unsigned int u32;
typedef unsigned short u16;

#define Cn 128
#define ICn 64
#define Nn 4096
#define Mn 1024

typedef __attribute__((ext_vector_type(8))) short s8v;   // 8 bf16 (4 VGPRs)
typedef __attribute__((ext_vector_type(4))) float f4v;   // 4 fp32 acc

union U8 { uint4 u; s8v v; };

__device__ __forceinline__ float asf(u32 u){ union{u32 i; float f;} v; v.i = u; return v.f; }
__device__ __forceinline__ float bf2f(u16 u){ return asf(((u32)u) << 16); }
// HW packed f32->bf16 (RNE)
__device__ __forceinline__ u32 pk2(float lo, float hi){
    u32 r;
    asm("v_cvt_pk_bf16_f32 %0, %1, %2" : "=v"(r) : "v"(lo), "v"(hi));
    return r;
}
__device__ __forceinline__ u16 f2bf(float f){ return (u16)pk2(f, f); }

// ---------------------------------------------------------------------------
// K1: per (row-pair r, half-width wb, batch b):
//   stage x^T bf16 (swizzled), W1/W4 bf16, u3 = w5[:64].W3;
//   dual conv MFMA -> pool a1 -> xg_o (bf16, *(1/1024) fold), pool a4 -> p_o;
//   t_o = u3.x + c3. g-MFMA/W2 phases REMOVED (k_back does the matmul).
// LDS u16 smem[35080] (~70.2 KB, 2 blocks/CU):
//   xsT @0 [64][136]; w1t @8704; w4t @17408; u3s @26112 f32[129];
//   ph0 @26372 f32[32][68] (a1); ph1 @30724 f32[32][68] (a4)
// ---------------------------------------------------------------------------
__global__ __launch_bounds__(256) void k_conv(
    const float* __restrict__ x,
    const float* __restrict__ w1, const float* __restrict__ b1,
    const float* __restrict__ w3, const float* __restrict__ b3,
    const float* __restrict__ w4, const float* __restrict__ b4,
    const float* __restrict__ w5,
    float* __restrict__ t_o, float* __restrict__ p_o, u16* __restrict__ xg_o)
{
    const int tile = blockIdx.x;   // 0..63
    const int r  = tile >> 1;      // row-pair 0..31
    const int wb = tile & 1;       // half-width 0..1
    const int b  = blockIdx.y;
    const int tid = threadIdx.x;

    __shared__ __align__(16) u16 smem[35080];
    u16* xsT = smem;                    // [64][136]
    u16* w1t = smem + 8704;             // [64][136]
    u16* w4t = smem + 17408;            // [64][136]
    float* u3s = (float*)&smem[26112];  // [129]
    float* ph0 = (float*)&smem[26372];  // [32][68]
    float* ph1 = (float*)&smem[30724];  // [32][68]

    // ---- stage x^T as bf16 channel-pairs, swizzled ----
    #pragma unroll
    for (int it = 0; it < 4; ++it) {
        int f = tid + 256 * it;        // 1024 tasks: cp = f>>4, rem = f&15
        int cp = f >> 4, rem = f & 15;
        int rl = rem >> 3, wq = rem & 7;
        const float* src = x + ((size_t)(b * Cn + 2 * cp)) * Nn + (2 * r + rl) * 64 + 32 * wb + 4 * wq;
        float4 v0 = *(const float4*)src;
        float4 v1 = *(const float4*)(src + Nn);
        int lp0 = rl * 32 + 4 * wq;
        int cS = (2 * cp) ^ (wq << 3);
        *(u32*)&xsT[(lp0 + 0) * 136 + cS] = pk2(v0.x, v1.x);
        *(u32*)&xsT[(lp0 + 1) * 136 + cS] = pk2(v0.y, v1.y);
        *(u32*)&xsT[(lp0 + 2) * 136 + cS] = pk2(v0.z, v1.z);
        *(u32*)&xsT[(lp0 + 3) * 136 + cS] = pk2(v0.w, v1.w);
    }
    // ---- stage W1, W4 ----
    #pragma unroll
    for (int it = 0; it < 4; ++it) {
        int f = tid + 256 * it;        // 1024 groups of 8: ic = f>>4, cq = f&15
        int ic = f >> 4, cq = f & 15;
        const float4* s1 = (const float4*)&w1[f * 8];
        const float4* s4 = (const float4*)&w4[f * 8];
        float4 a0 = s1[0], a1v = s1[1];
        float4 d0 = s4[0], d1v = s4[1];
        uint4 A, D;
        A.x = pk2(a0.x, a0.y); A.y = pk2(a0.z, a0.w); A.z = pk2(a1v.x, a1v.y); A.w = pk2(a1v.z, a1v.w);
        D.x = pk2(d0.x, d0.y); D.y = pk2(d0.z, d0.w); D.z = pk2(d1v.x, d1v.y); D.w = pk2(d1v.z, d1v.w);
        *(uint4*)&w1t[ic * 136 + 8 * cq] = A;
        *(uint4*)&w4t[ic * 136 + 8 * cq] = D;
    }
    // ---- u3 = w5[:64].W3 ----
    if (tid < 128) {
        float s0 = 0.f, s1 = 0.f;
        #pragma unroll 8
        for (int ic = 0; ic < 64; ic += 2) {
            s0 += w5[ic]     * w3[ic * Cn + tid];
            s1 += w5[ic + 1] * w3[(ic + 1) * Cn + tid];
        }
        u3s[tid] = s0 + s1;
    } else if (tid == 128) {
        float s = 0.f;
        #pragma unroll 16
        for (int ic = 0; ic < 64; ++ic) s += w5[ic] * b3[ic];
        u3s[128] = s;
    }
    __syncthreads();

    const int lane = tid & 63;
    const int wv   = tid >> 6;
    const int col  = lane & 15;
    const int quad = lane >> 4;

    // ---- dual conv MFMA: D[ic][lp] ----
    f4v acc1[4] = {}, acc4[4] = {};
    const u16* xrow = &xsT[(16 * wv + col) * 136];
    const int xsw = (((16 * wv + col) >> 2) & 7) << 3;
    #pragma unroll
    for (int kb = 0; kb < 4; ++kb) {
        s8v bx = *(const s8v*)&xrow[(kb * 32 + quad * 8) ^ xsw];
        #pragma unroll
        for (int icb = 0; icb < 4; ++icb) {
            s8v a1 = *(const s8v*)&w1t[(icb * 16 + col) * 136 + kb * 32 + quad * 8];
            s8v a4 = *(const s8v*)&w4t[(icb * 16 + col) * 136 + kb * 32 + quad * 8];
            acc1[icb] = __builtin_amdgcn_mfma_f32_16x16x32_bf16(a1, bx, acc1[icb], 0, 0, 0);
            acc4[icb] = __builtin_amdgcn_mfma_f32_16x16x32_bf16(a4, bx, acc4[icb], 0, 0, 0);
        }
    }

    // ---- both horizontal pair-max pools (a1->ph0, a4->ph1), one phase ----
    const int lp = 16 * wv + col;
    const int rl = lp >> 5, wl = lp & 31, pw = wl >> 1;
    const bool wr = (wl & 1) == 0;
    #pragma unroll
    for (int icb = 0; icb < 4; ++icb)
        #pragma unroll
        for (int reg = 0; reg < 4; ++reg) {
            float v1 = acc1[icb][reg];
            float m1 = fmaxf(v1, __shfl_xor(v1, 1, 64));
            float v4 = acc4[icb][reg];
            float m4 = fmaxf(v4, __shfl_xor(v4, 1, 64));
            if (wr) {
                ph0[(rl * 16 + pw) * 68 + icb * 16 + quad * 4 + reg] = m1;
                ph1[(rl * 16 + pw) * 68 + icb * 16 + quad * 4 + reg] = m4;
            }
        }
    __syncthreads();   // MFMA LDS reads done + ph ready

    // ---- xg_o = (vpool(a1) + b1) / 1024 as bf16 ----
    #pragma unroll
    for (int it = 0; it < 4; ++it) {
        int e = tid + 256 * it;        // 1024: pwq = e>>6, ic = e&63
        int pwq = e >> 6, ic = e & 63;
        float v = fmaxf(ph0[pwq * 68 + ic], ph0[(16 + pwq) * 68 + ic]) + b1[ic];
        xg_o[((size_t)(b * 64 + ic) << 10) + r * 32 + wb * 16 + pwq] = f2bf(v * (1.0f / 1024.0f));
    }
    // ---- t = u3.x + c3, all 256 threads (4 lanes per pixel) ----
    {
        int px = tid >> 2, part = tid & 3;
        const int tsw = ((px >> 2) & 7) << 3;
        const u16* xr = &xsT[px * 136];
        float s = 0.f;
        #pragma unroll
        for (int cq = 0; cq < 4; ++cq) {
            int u = part * 32 + cq * 8;
            s8v xv = *(const s8v*)&xr[u ^ tsw];
            #pragma unroll
            for (int j = 0; j < 8; ++j) s += u3s[u + j] * bf2f((u16)xv[j]);
        }
        s += __shfl_xor(s, 1, 64);
        s += __shfl_xor(s, 2, 64);
        if (part == 0)
            t_o[(size_t)b * Nn + (2 * r + (px >> 5)) * 64 + 32 * wb + (px & 31)] = s + u3s[128];
    }
    // ---- p from a4 pool ----
    if (tid < 16) {
        float s = 0.f;
        #pragma unroll 8
        for (int ic = 0; ic < 64; ++ic) {
            float pv = fmaxf(ph1[tid * 68 + ic], ph1[(16 + tid) * 68 + ic]) + b4[ic];
            s += w5[64 + ic] * pv;
        }
        p_o[(size_t)b * Mn + r * 32 + wb * 16 + tid] = s;
    }
}

// ---------------------------------------------------------------------------
// K2 (the whole back half): grid (32 n-tiles, 8 b) x 512 thr, 1 block/CU.
// y[n,ic] = sum_m relu(t[n]+p[m]) * xg[ic][m]  via MFMA with A=feats generated
// in registers as bf16 hi+lo (split precision). Then out[co][n] =
// sum_ic w2[co][ic]*y[n][ic] via MFMA (y packed bf16 hi/lo in LDS), BN + x.
// LDS ~87.8 KB: xgs 2x16K (XOR-swz) | w2t 16K (swz) | ylds u32[64][129] |
// pl[1024] | tl[128] | scb[2][128]
// ---------------------------------------------------------------------------
__global__ __launch_bounds__(512) void k_back(
    const float* __restrict__ x, const float* __restrict__ t,
    const float* __restrict__ p, const u16* __restrict__ xg,
    const float* __restrict__ w2, const float* __restrict__ b2,
    const float* __restrict__ gamma, const float* __restrict__ beta,
    const float* __restrict__ mean, const float* __restrict__ var,
    float* __restrict__ out)
{
    const int nt = blockIdx.x;     // 0..31
    const int b  = blockIdx.y;
    const int tid = threadIdx.x;

    __shared__ __align__(16) char smem[87808];
    u16* xgs  = (u16*)smem;                  // [2][64*128]
    u16* w2t  = (u16*)(smem + 32768);        // [128*64]
    u32* ylds = (u32*)(smem + 49152);        // [64*129]
    float* pl = (float*)(smem + 82176);      // [1024]
    float* tl = (float*)(smem + 86272);      // [128]
    float* sc0 = (float*)(smem + 86784);     // [128]
    float* sc1 = (float*)(smem + 87296);     // [128]

    // ---- phase 0 staging ----
    pl[tid]       = p[b * Mn + tid];
    pl[tid + 512] = p[b * Mn + tid + 512];
    if (tid < 128) {
        tl[tid] = t[(size_t)b * Nn + nt * 128 + tid];
    } else if (tid < 256) {
        int co = tid - 128;
        float s = gamma[co] * rsqrtf(var[co] + 1e-5f);
        sc0[co] = s;
        sc1[co] = (b2[co] - mean[co]) * s + beta[co];
    }
    #pragma unroll
    for (int it = 0; it < 2; ++it) {
        int f = tid + 512 * it;            // 1024 chunks: co = f>>3, iq = f&7
        int co = f >> 3, iq = f & 7;
        const float4* s2 = (const float4*)&w2[co * 64 + iq * 8];
        float4 a0 = s2[0], a1v = s2[1];
        uint4 V;
        V.x = pk2(a0.x, a0.y); V.y = pk2(a0.z, a0.w); V.z = pk2(a1v.x, a1v.y); V.w = pk2(a1v.z, a1v.w);
        *(uint4*)&w2t[co * 64 + ((iq * 8) ^ ((co & 7) << 3))] = V;
    }
    #pragma unroll
    for (int it = 0; it < 2; ++it) {
        int f = tid + 512 * it;            // 1024 chunks: ic = f>>4, mc = f&15
        int ic = f >> 4, mc = f & 15;
        uint4 V = *(const uint4*)&xg[((size_t)(b * 64 + ic) << 10) + mc * 8];
        *(uint4*)&xgs[ic * 128 + ((mc * 8) ^ ((ic & 7) << 3))] = V;
    }
    __syncthreads();

    const int lane = tid & 63;
    const int wv   = tid >> 6;         // 0..7
    const int col  = lane & 15;
    const int quad = lane >> 4;
    const int nb   = wv * 16;
    const int xsw  = (col & 7) << 3;
    const float tval = tl[nb + col];

    // ---- matmul1: y[n][ic] += (hi+lo)(feats) x xg, m-tiles of 128 ----
    f4v acc[4] = {};
    for (int mt = 0; mt < 8; ++mt) {
        uint4 pf0, pf1;
        if (mt < 7) {
            int f0 = tid, f1 = tid + 512;
            pf0 = *(const uint4*)&xg[((size_t)(b * 64 + (f0 >> 4)) << 10) + (mt + 1) * 128 + (f0 & 15) * 8];
            pf1 = *(const uint4*)&xg[((size_t)(b * 64 + (f1 >> 4)) << 10) + (mt + 1) * 128 + (f1 & 15) * 8];
        }
        const u16* xb = xgs + (mt & 1) * 8192;
        #pragma unroll
        for (int kb = 0; kb < 4; ++kb) {
            int mb = mt * 128 + kb * 32;
            float4 pa = *(const float4*)&pl[mb + quad * 8];
            float4 pb = *(const float4*)&pl[mb + quad * 8 + 4];
            float f0 = fmaxf(tval + pa.x, 0.f), f1 = fmaxf(tval + pa.y, 0.f);
            float f2 = fmaxf(tval + pa.z, 0.f), f3 = fmaxf(tval + pa.w, 0.f);
            float f4 = fmaxf(tval + pb.x, 0.f), f5 = fmaxf(tval + pb.y, 0.f);
            float f6 = fmaxf(tval + pb.z, 0.f), f7 = fmaxf(tval + pb.w, 0.f);
            U8 hi, lo;
            hi.u.x = pk2(f0, f1); hi.u.y = pk2(f2, f3); hi.u.z = pk2(f4, f5); hi.u.w = pk2(f6, f7);
            float l0 = f0 - asf(hi.u.x << 16), l1 = f1 - asf(hi.u.x & 0xffff0000u);
            float l2 = f2 - asf(hi.u.y << 16), l3 = f3 - asf(hi.u.y & 0xffff0000u);
            float l4 = f4 - asf(hi.u.z << 16), l5 = f5 - asf(hi.u.z & 0xffff0000u);
            float l6 = f6 - asf(hi.u.w << 16), l7 = f7 - asf(hi.u.w & 0xffff0000u);
            lo.u.x = pk2(l0, l1); lo.u.y = pk2(l2, l3); lo.u.z = pk2(l4, l5); lo.u.w = pk2(l6, l7);
            #pragma unroll
            for (int icb = 0; icb < 4; ++icb) {
                const s8v bf = *(const s8v*)&xb[(icb * 16 + col) * 128 + ((kb * 32 + quad * 8) ^ xsw)];
                acc[icb] = __builtin_amdgcn_mfma_f32_16x16x32_bf16(hi.v, bf, acc[icb], 0, 0, 0);
                acc[icb] = __builtin_amdgcn_mfma_f32_16x16x32_bf16(lo.v, bf, acc[icb], 0, 0, 0);
            }
        }
        if (mt < 7) {
            int f0 = tid, f1 = tid + 512;
            u16* dst = xgs + ((mt + 1) & 1) * 8192;
            *(uint4*)&dst[(f0 >> 4) * 128 + (((f0 & 15) * 8) ^ (((f0 >> 4) & 7) << 3))] = pf0;
            *(uint4*)&dst[(f1 >> 4) * 128 + (((f1 & 15) * 8) ^ (((f1 >> 4) & 7) << 3))] = pf1;
        }
        __syncthreads();
    }

    // ---- y -> LDS as packed bf16 hi|lo ----
    #pragma unroll
    for (int icb = 0; icb < 4; ++icb)
        #pragma unroll
        for (int reg = 0; reg < 4; ++reg) {
            float f = acc[icb][reg];
            u32 h = pk2(f, f) & 0xffffu;
            float lo = f - asf(h << 16);
            u32 l = pk2(lo, lo) & 0xffffu;
            ylds[(icb * 16 + col) * 129 + nb + quad * 4 + reg] = h | (l << 16);
        }
    __syncthreads();

    // ---- matmul2: out[co][n] = w2 x y ----
    f4v acc2[8] = {};
    #pragma unroll
    for (int kb = 0; kb < 2; ++kb) {
        u32 yv[8];
        #pragma unroll
        for (int j = 0; j < 8; ++j)
            yv[j] = ylds[(kb * 32 + quad * 8 + j) * 129 + nb + col];
        U8 bhi, blo;
        bhi.u.x = (yv[0] & 0xffffu) | (yv[1] << 16);
        bhi.u.y = (yv[2] & 0xffffu) | (yv[3] << 16);
        bhi.u.z = (yv[4] & 0xffffu) | (yv[5] << 16);
        bhi.u.w = (yv[6] & 0xffffu) | (yv[7] << 16);
        blo.u.x = (yv[0] >> 16) | (yv[1] & 0xffff0000u);
        blo.u.y = (yv[2] >> 16) | (yv[3] & 0xffff0000u);
        blo.u.z = (yv[4] >> 16) | (yv[5] & 0xffff0000u);
        blo.u.w = (yv[6] >> 16) | (yv[7] & 0xffff0000u);
        #pragma unroll
        for (int cob = 0; cob < 8; ++cob) {
            const s8v a = *(const s8v*)&w2t[(cob * 16 + col) * 64 + ((kb * 32 + quad * 8) ^ xsw)];
            acc2[cob] = __builtin_amdgcn_mfma_f32_16x16x32_bf16(a, bhi.v, acc2[cob], 0, 0, 0);
            acc2[cob] = __builtin_amdgcn_mfma_f32_16x16x32_bf16(a, blo.v, acc2[cob], 0, 0, 0);
        }
    }

    // ---- epilogue: BN + residual ----
    const int n = nt * 128 + nb + col;
    #pragma unroll
    for (int cob = 0; cob < 8; ++cob)
        #pragma unroll
        for (int reg = 0; reg < 4; ++reg) {
            int co = cob * 16 + quad * 4 + reg;
            size_t gi = ((size_t)(b * Cn + co)) * Nn + n;
            out[gi] = acc2[cob][reg] * sc0[co] + sc1[co] + x[gi];
        }
}

// ---------------------------------------------------------------------------
extern "C" void kernel_launch(void* const* d_in, const int* in_sizes, int n_in,
                              void* d_out, int out_size, void* d_ws, size_t ws_size,
                              hipStream_t stream)
{
    const float* x  = (const float*)d_in[0];
    const float* w1 = (const float*)d_in[1];
    const float* b1 = (const float*)d_in[2];
    const float* w3 = (const float*)d_in[3];
    const float* b3 = (const float*)d_in[4];
    const float* w4 = (const float*)d_in[5];
    const float* b4 = (const float*)d_in[6];
    const float* w5 = (const float*)d_in[7];
    const float* w2 = (const float*)d_in[8];
    const float* b2 = (const float*)d_in[9];
    const float* gm = (const float*)d_in[10];
    const float* bt = (const float*)d_in[11];
    const float* mn = (const float*)d_in[12];
    const float* vr = (const float*)d_in[13];
    float* out = (float*)d_out;

    float* ws = (float*)d_ws;
    const size_t FTOT = 3823872;           // floats (~15.3 MB) — same reservation
    if (ws_size < FTOT * sizeof(float)) return;

    float* t_w  = ws;                      // 32768 fl
    float* p_w  = ws + 32768;              // 8192 fl
    u16*   xg_w = (u16*)(ws + 40960);      // 65536 u16 = 32768 fl

    k_conv<<<dim3(64, 8), 256, 0, stream>>>(x, w1, b1, w3, b3, w4, b4, w5,
                                            t_w, p_w, xg_w);
    k_back<<<dim3(32, 8), 512, 0, stream>>>(x, t_w, p_w, xg_w,
                                            w2, b2, gm, bt, mn, vr, out);
}